// Round 1
// baseline (18396.118 us; speedup 1.0000x reference)
//
#include <hip/hip_runtime.h>
#include <math.h>

#define NTOK 144
#define CDIM 512
#define NH 16
#define DHH 32

// ---------------------------------------------------------------------------
// Kernel 1: CPB MLP  tbl[row][h] = sum_j w2[h][j] * relu(w1[j]·coord + b1[j])
// ---------------------------------------------------------------------------
__global__ __launch_bounds__(512) void cpb_mlp_kernel(
    const float* __restrict__ rel_table, const float* __restrict__ w1,
    const float* __restrict__ b1, const float* __restrict__ w2,
    float* __restrict__ tbl)
{
    int row = blockIdx.x;          // 0..528
    int t = threadIdx.x;           // 512
    float c0 = rel_table[row * 2 + 0], c1 = rel_table[row * 2 + 1];
    float hv = fmaxf(w1[t * 2 + 0] * c0 + w1[t * 2 + 1] * c1 + b1[t], 0.f);
    __shared__ float hid[512];
    hid[t] = hv;
    __syncthreads();
    int h = t & 15, seg = t >> 4;  // 32 segments of 16
    float p = 0.f;
#pragma unroll
    for (int jj = 0; jj < 16; ++jj)
        p += w2[h * 512 + seg * 16 + jj] * hid[seg * 16 + jj];
    __shared__ float part[512];
    part[t] = p;
    __syncthreads();
    for (int s = 256; s >= 16; s >>= 1) {
        if (t < s) part[t] += part[t + s];
        __syncthreads();
    }
    if (t < 16) tbl[row * 16 + t] = part[t];
}

// ---------------------------------------------------------------------------
// Kernel 2: bias[h][i][j] = 16*sigmoid(tbl[rel_index[i][j]][h])
// ---------------------------------------------------------------------------
__global__ __launch_bounds__(256) void bias_kernel(
    const float* __restrict__ tbl, const int* __restrict__ rel_index,
    float* __restrict__ bias)
{
    int idx = blockIdx.x * 256 + threadIdx.x;   // 16*144*144 = 331776 exact
    int h = idx / (NTOK * NTOK);
    int ij = idx - h * (NTOK * NTOK);
    float v = tbl[rel_index[ij] * 16 + h];
    bias[idx] = 16.f / (1.f + __expf(-v));
}

// ---------------------------------------------------------------------------
// Kernel 3: fused per-(b,h) window attention.
//   phase 1: qkv = x_b @ Wqkv_h^T   (144x512 @ 512x96), per-thread 9x3 tile
//   phase 2: row-normalize q (x scale) and k
//   phase 3: per-wave rows: scores (k in regs) -> softmax -> PV (v in regs)
// LDS swizzle: 16B slot s stored at s ^ (row & (nslots-1))  (T2-style XOR)
// ---------------------------------------------------------------------------
__global__ __launch_bounds__(512) void attn_kernel(
    const float* __restrict__ x, const float* __restrict__ mask,
    const float* __restrict__ qkv_w, const float* __restrict__ logit_scale,
    const float* __restrict__ bias, float* __restrict__ attn_out)
{
    __shared__ __align__(16) float xs[NTOK][64];   // 36.9 KB, 16 slots/row
    __shared__ __align__(16) float wsm[96][64];    // 24.6 KB
    __shared__ __align__(16) float qs[NTOK][32];   // 18.4 KB, 8 slots/row
    __shared__ __align__(16) float ks[NTOK][32];
    __shared__ __align__(16) float vs[NTOK][32];
    __shared__ __align__(16) float ps[8][152];     // 4.9 KB (152: keeps rows 16B-aligned)

    const int t = threadIdx.x;
    const int b = blockIdx.x >> 4;
    const int h = blockIdx.x & 15;
    const int tx = t & 31;      // col within 32 (= head dim d)
    const int ty = t >> 5;      // 0..15 (row group)

    // ---------------- phase 1: QKV GEMM ----------------
    float acc[9][3];
#pragma unroll
    for (int i = 0; i < 9; ++i) { acc[i][0] = 0.f; acc[i][1] = 0.f; acc[i][2] = 0.f; }

    for (int kt = 0; kt < 8; ++kt) {           // K tiles of 64
        // stage x tile (144 x 64) swizzled
#pragma unroll
        for (int e = 0; e < 5; ++e) {
            int idx = e * 512 + t;
            if (idx < NTOK * 16) {
                int row = idx >> 4, s = idx & 15;
                float4 v = *(const float4*)(x + ((b * NTOK + row) * CDIM + kt * 64 + 4 * s));
                ((float4*)xs)[row * 16 + (s ^ (row & 15))] = v;
            }
        }
        // stage W tile (96 x 64) swizzled; row r -> qkv channel (r/32)*512 + h*32 + r%32
#pragma unroll
        for (int e = 0; e < 3; ++e) {
            int idx = e * 512 + t;             // < 1536 exact
            int row = idx >> 4, s = idx & 15;
            int grow = (row >> 5) * CDIM + h * DHH + (row & 31);
            float4 v = *(const float4*)(qkv_w + (grow * CDIM + kt * 64 + 4 * s));
            ((float4*)wsm)[row * 16 + (s ^ (row & 15))] = v;
        }
        __syncthreads();
#pragma unroll
        for (int s = 0; s < 16; ++s) {
            float4 a4[9], b4[3];
#pragma unroll
            for (int ri = 0; ri < 9; ++ri) {
                int row = ty + 16 * ri;
                a4[ri] = ((const float4*)xs)[row * 16 + (s ^ (row & 15))];
            }
#pragma unroll
            for (int ci = 0; ci < 3; ++ci) {
                int r = tx + 32 * ci;
                b4[ci] = ((const float4*)wsm)[r * 16 + (s ^ (r & 15))];
            }
#pragma unroll
            for (int ri = 0; ri < 9; ++ri)
#pragma unroll
                for (int ci = 0; ci < 3; ++ci)
                    acc[ri][ci] += a4[ri].x * b4[ci].x + a4[ri].y * b4[ci].y +
                                   a4[ri].z * b4[ci].z + a4[ri].w * b4[ci].w;
        }
        __syncthreads();
    }
    // scatter accumulators to q/k/v (swizzled element store)
#pragma unroll
    for (int ri = 0; ri < 9; ++ri) {
        int row = ty + 16 * ri;
        int off = 4 * ((tx >> 2) ^ (row & 7)) + (tx & 3);
        qs[row][off] = acc[ri][0];
        ks[row][off] = acc[ri][1];
        vs[row][off] = acc[ri][2];
    }
    __syncthreads();

    // ---------------- phase 2: normalize rows ----------------
    {
        float sc = __expf(fminf(logit_scale[h], 4.60517019f));  // exp(min(ls, log 100))
        int r = -1; float* base = nullptr;
        if (t < NTOK) { r = t; base = &qs[r][0]; }
        else if (t >= 256 && t < 256 + NTOK) { r = t - 256; base = &ks[r][0]; sc = 1.f; }
        if (r >= 0) {
            float4* b4p = (float4*)base;
            float4 v[8];
            float ss = 0.f;
#pragma unroll
            for (int s = 0; s < 8; ++s) {
                v[s] = b4p[s];
                ss += v[s].x * v[s].x + v[s].y * v[s].y + v[s].z * v[s].z + v[s].w * v[s].w;
            }
            float rn = sc / sqrtf(ss);
#pragma unroll
            for (int s = 0; s < 8; ++s) {
                v[s].x *= rn; v[s].y *= rn; v[s].z *= rn; v[s].w *= rn;
                b4p[s] = v[s];
            }
        }
    }
    __syncthreads();

    // ---------------- phase 3: scores + softmax + PV ----------------
    const int lane = t & 63, wid = t >> 6;
    const int half = lane >> 5, d = lane & 31;

    // k rows in registers: j = lane, lane+64, 128+(lane&15) (clamped; masked later)
    float4 kr0[8], kr1[8], kr2[8];
    {
        int r0 = lane, r1 = lane + 64, r2 = 128 + (lane & 15);
#pragma unroll
        for (int s = 0; s < 8; ++s) {
            kr0[s] = ((const float4*)ks)[r0 * 8 + (s ^ (r0 & 7))];
            kr1[s] = ((const float4*)ks)[r1 * 8 + (s ^ (r1 & 7))];
            kr2[s] = ((const float4*)ks)[r2 * 8 + (s ^ (r2 & 7))];
        }
    }
    // v column d for this lane's j-half in registers
    float4 vr[18];
#pragma unroll
    for (int s18 = 0; s18 < 18; ++s18) {
        int j0 = half * 72 + 4 * s18;
        float a0 = vs[j0 + 0][4 * ((d >> 2) ^ ((j0 + 0) & 7)) + (d & 3)];
        float a1 = vs[j0 + 1][4 * ((d >> 2) ^ ((j0 + 1) & 7)) + (d & 3)];
        float a2 = vs[j0 + 2][4 * ((d >> 2) ^ ((j0 + 2) & 7)) + (d & 3)];
        float a3 = vs[j0 + 3][4 * ((d >> 2) ^ ((j0 + 3) & 7)) + (d & 3)];
        vr[s18] = make_float4(a0, a1, a2, a3);
    }

    const float* brow = bias + h * NTOK * NTOK;
    const float* mrow = mask + (b & 63) * NTOK * NTOK;
    const int j2c = 128 + (lane & 15);
    const float NEG = -1e30f;

    for (int it = 0; it < 18; ++it) {
        int i = it * 8 + wid;
        float s0 = 0.f, s1 = 0.f, s2 = 0.f;
#pragma unroll
        for (int s = 0; s < 8; ++s) {
            float4 q4 = ((const float4*)qs)[i * 8 + (s ^ (i & 7))];
            s0 += q4.x * kr0[s].x + q4.y * kr0[s].y + q4.z * kr0[s].z + q4.w * kr0[s].w;
            s1 += q4.x * kr1[s].x + q4.y * kr1[s].y + q4.z * kr1[s].z + q4.w * kr1[s].w;
            s2 += q4.x * kr2[s].x + q4.y * kr2[s].y + q4.z * kr2[s].z + q4.w * kr2[s].w;
        }
        int rowoff = i * NTOK;
        s0 += brow[rowoff + lane] + mrow[rowoff + lane];
        s1 += brow[rowoff + 64 + lane] + mrow[rowoff + 64 + lane];
        s2 += brow[rowoff + j2c] + mrow[rowoff + j2c];
        s2 = (lane < 16) ? s2 : NEG;

        float m = fmaxf(fmaxf(s0, s1), s2);
#pragma unroll
        for (int off = 32; off >= 1; off >>= 1) m = fmaxf(m, __shfl_xor(m, off));
        float e0 = __expf(s0 - m), e1 = __expf(s1 - m);
        float e2 = (lane < 16) ? __expf(s2 - m) : 0.f;
        float sum = e0 + e1 + e2;
#pragma unroll
        for (int off = 32; off >= 1; off >>= 1) sum += __shfl_xor(sum, off);
        float inv = 1.f / sum;
        ps[wid][lane] = e0 * inv;
        ps[wid][64 + lane] = e1 * inv;
        if (lane < 16) ps[wid][128 + lane] = e2 * inv;

        float o = 0.f;
        const float4* p4p = (const float4*)&ps[wid][half * 72];
#pragma unroll
        for (int s18 = 0; s18 < 18; ++s18) {
            float4 p4 = p4p[s18];
            o += p4.x * vr[s18].x + p4.y * vr[s18].y + p4.z * vr[s18].z + p4.w * vr[s18].w;
        }
        o += __shfl_xor(o, 32);
        if (lane < 32)
            attn_out[(b * NTOK + i) * CDIM + h * DHH + d] = o;
    }
}

// ---------------------------------------------------------------------------
// Kernel 4: out = attn_out @ proj_w^T + proj_b   (73728x512 @ 512x512)
// 128x128 tile, BK=16, 256 threads, 8x8 per thread (interleaved 16-stride)
// ---------------------------------------------------------------------------
__global__ __launch_bounds__(256) void proj_kernel(
    const float* __restrict__ A, const float* __restrict__ W,
    const float* __restrict__ pb, float* __restrict__ out)
{
    __shared__ float as_[16][132];
    __shared__ float bs_[16][132];
    const int t = threadIdx.x;
    const int tx = t & 15, ty = (t >> 4) & 15;
    const int m0 = blockIdx.y * 128, n0 = blockIdx.x * 128;
    float acc[8][8] = {};

    for (int kt = 0; kt < 32; ++kt) {
#pragma unroll
        for (int e = 0; e < 8; ++e) {
            int idx = e * 256 + t;             // 2048 exact
            int row = idx >> 4, kk = idx & 15;
            as_[kk][row] = A[(size_t)(m0 + row) * CDIM + kt * 16 + kk];
            bs_[kk][row] = W[(size_t)(n0 + row) * CDIM + kt * 16 + kk];
        }
        __syncthreads();
#pragma unroll
        for (int kk = 0; kk < 16; ++kk) {
            float a[8], bb[8];
#pragma unroll
            for (int i = 0; i < 8; ++i) a[i] = as_[kk][ty + 16 * i];
#pragma unroll
            for (int j = 0; j < 8; ++j) bb[j] = bs_[kk][tx + 16 * j];
#pragma unroll
            for (int i = 0; i < 8; ++i)
#pragma unroll
                for (int j = 0; j < 8; ++j)
                    acc[i][j] += a[i] * bb[j];
        }
        __syncthreads();
    }
#pragma unroll
    for (int i = 0; i < 8; ++i) {
        int m = m0 + ty + 16 * i;
#pragma unroll
        for (int j = 0; j < 8; ++j) {
            int n = n0 + tx + 16 * j;
            out[(size_t)m * CDIM + n] = acc[i][j] + pb[n];
        }
    }
}

// ---------------------------------------------------------------------------
extern "C" void kernel_launch(void* const* d_in, const int* in_sizes, int n_in,
                              void* d_out, int out_size, void* d_ws, size_t ws_size,
                              hipStream_t stream) {
    const float* x           = (const float*)d_in[0];
    const float* mask        = (const float*)d_in[1];
    const float* qkv_w       = (const float*)d_in[2];
    const float* logit_scale = (const float*)d_in[3];
    const float* cpb_w1      = (const float*)d_in[4];
    const float* cpb_b1      = (const float*)d_in[5];
    const float* cpb_w2      = (const float*)d_in[6];
    const float* proj_w      = (const float*)d_in[7];
    const float* proj_b      = (const float*)d_in[8];
    const float* rel_table   = (const float*)d_in[9];
    const int*   rel_index   = (const int*)d_in[10];
    float* out = (float*)d_out;

    // workspace layout: attn_out (151 MB) | bias (1.3 MB) | tbl (34 KB)
    char* ws = (char*)d_ws;
    float* attn_out = (float*)ws;
    float* bias = (float*)(ws + (size_t)512 * NTOK * CDIM * 4);
    float* tbl  = (float*)(ws + (size_t)512 * NTOK * CDIM * 4 + (size_t)NH * NTOK * NTOK * 4);

    cpb_mlp_kernel<<<529, 512, 0, stream>>>(rel_table, cpb_w1, cpb_b1, cpb_w2, tbl);
    bias_kernel<<<(NH * NTOK * NTOK) / 256, 256, 0, stream>>>(tbl, rel_index, bias);
    attn_kernel<<<512 * NH, 512, 0, stream>>>(x, mask, qkv_w, logit_scale, bias, attn_out);
    proj_kernel<<<dim3(4, 576), 256, 0, stream>>>(attn_out, proj_w, proj_b, out);
}

// Round 3
// 18383.974 us; speedup vs baseline: 1.0007x; 1.0007x over previous
//
#include <hip/hip_runtime.h>
#include <math.h>

#define NTOK 144
#define CDIM 512
#define NH 16
#define DHH 32

// ---------------------------------------------------------------------------
// Kernel 1: CPB MLP  tbl[row][h] = sum_j w2[h][j] * relu(w1[j]·coord + b1[j])
// ---------------------------------------------------------------------------
__global__ __launch_bounds__(512) void cpb_mlp_kernel(
    const float* __restrict__ rel_table, const float* __restrict__ w1,
    const float* __restrict__ b1, const float* __restrict__ w2,
    float* __restrict__ tbl)
{
    int row = blockIdx.x;          // 0..528
    int t = threadIdx.x;           // 512
    float c0 = rel_table[row * 2 + 0], c1 = rel_table[row * 2 + 1];
    float hv = fmaxf(w1[t * 2 + 0] * c0 + w1[t * 2 + 1] * c1 + b1[t], 0.f);
    __shared__ float hid[512];
    hid[t] = hv;
    __syncthreads();
    int h = t & 15, seg = t >> 4;  // 32 segments of 16
    float p = 0.f;
#pragma unroll
    for (int jj = 0; jj < 16; ++jj)
        p += w2[h * 512 + seg * 16 + jj] * hid[seg * 16 + jj];
    __shared__ float part[512];
    part[t] = p;
    __syncthreads();
    for (int s = 256; s >= 16; s >>= 1) {
        if (t < s) part[t] += part[t + s];
        __syncthreads();
    }
    if (t < 16) tbl[row * 16 + t] = part[t];
}

// ---------------------------------------------------------------------------
// Kernel 2: bias[h][i][j] = 16*sigmoid(tbl[rel_index[i][j]][h])
// ---------------------------------------------------------------------------
__global__ __launch_bounds__(256) void bias_kernel(
    const float* __restrict__ tbl, const int* __restrict__ rel_index,
    float* __restrict__ bias)
{
    int idx = blockIdx.x * 256 + threadIdx.x;   // 16*144*144 = 331776 exact
    int h = idx / (NTOK * NTOK);
    int ij = idx - h * (NTOK * NTOK);
    float v = tbl[rel_index[ij] * 16 + h];
    bias[idx] = 16.f / (1.f + __expf(-v));
}

// ---------------------------------------------------------------------------
// Kernel 3: fused per-(b,h) window attention.
//   phase 1: qkv = x_b @ Wqkv_h^T   (144x512 @ 512x96), per-thread 9x3 tile
//   phase 2: row-normalize q (x scale) and k
//   phase 3: per-wave rows: scores (k in regs) -> softmax -> PV (v in regs)
// LDS swizzle: 16B slot s stored at s ^ (row & (nslots-1))  (T2-style XOR)
// __launch_bounds__(512, 2): LDS (121.6KB) caps us at 1 block/CU = 2 waves/SIMD
// anyway, so allow 256 VGPRs -- phase 3 holds ~170 live regs (kr* 96 + vr 72);
// at the default 128-VGPR cap they all spilled to scratch (R1: 44.6 GB HBM
// writes, 18 ms). No occupancy cost to the 256 cap.
// ---------------------------------------------------------------------------
__global__ __launch_bounds__(512, 2) void attn_kernel(
    const float* __restrict__ x, const float* __restrict__ mask,
    const float* __restrict__ qkv_w, const float* __restrict__ logit_scale,
    const float* __restrict__ bias, float* __restrict__ attn_out)
{
    __shared__ __align__(16) float xs[NTOK][64];   // 36.9 KB, 16 slots/row
    __shared__ __align__(16) float wsm[96][64];    // 24.6 KB
    __shared__ __align__(16) float qs[NTOK][32];   // 18.4 KB, 8 slots/row
    __shared__ __align__(16) float ks[NTOK][32];
    __shared__ __align__(16) float vs[NTOK][32];
    __shared__ __align__(16) float ps[8][152];     // 4.9 KB (152: keeps rows 16B-aligned)

    const int t = threadIdx.x;
    const int b = blockIdx.x >> 4;
    const int h = blockIdx.x & 15;
    const int tx = t & 31;      // col within 32 (= head dim d)
    const int ty = t >> 5;      // 0..15 (row group)

    // ---------------- phase 1: QKV GEMM ----------------
    float acc[9][3];
#pragma unroll
    for (int i = 0; i < 9; ++i) { acc[i][0] = 0.f; acc[i][1] = 0.f; acc[i][2] = 0.f; }

    for (int kt = 0; kt < 8; ++kt) {           // K tiles of 64
        // stage x tile (144 x 64) swizzled
#pragma unroll
        for (int e = 0; e < 5; ++e) {
            int idx = e * 512 + t;
            if (idx < NTOK * 16) {
                int row = idx >> 4, s = idx & 15;
                float4 v = *(const float4*)(x + ((b * NTOK + row) * CDIM + kt * 64 + 4 * s));
                ((float4*)xs)[row * 16 + (s ^ (row & 15))] = v;
            }
        }
        // stage W tile (96 x 64) swizzled; row r -> qkv channel (r/32)*512 + h*32 + r%32
#pragma unroll
        for (int e = 0; e < 3; ++e) {
            int idx = e * 512 + t;             // < 1536 exact
            int row = idx >> 4, s = idx & 15;
            int grow = (row >> 5) * CDIM + h * DHH + (row & 31);
            float4 v = *(const float4*)(qkv_w + (grow * CDIM + kt * 64 + 4 * s));
            ((float4*)wsm)[row * 16 + (s ^ (row & 15))] = v;
        }
        __syncthreads();
#pragma unroll
        for (int s = 0; s < 16; ++s) {
            float4 a4[9], b4[3];
#pragma unroll
            for (int ri = 0; ri < 9; ++ri) {
                int row = ty + 16 * ri;
                a4[ri] = ((const float4*)xs)[row * 16 + (s ^ (row & 15))];
            }
#pragma unroll
            for (int ci = 0; ci < 3; ++ci) {
                int r = tx + 32 * ci;
                b4[ci] = ((const float4*)wsm)[r * 16 + (s ^ (r & 15))];
            }
#pragma unroll
            for (int ri = 0; ri < 9; ++ri)
#pragma unroll
                for (int ci = 0; ci < 3; ++ci)
                    acc[ri][ci] += a4[ri].x * b4[ci].x + a4[ri].y * b4[ci].y +
                                   a4[ri].z * b4[ci].z + a4[ri].w * b4[ci].w;
        }
        __syncthreads();
    }
    // scatter accumulators to q/k/v (swizzled element store)
#pragma unroll
    for (int ri = 0; ri < 9; ++ri) {
        int row = ty + 16 * ri;
        int off = 4 * ((tx >> 2) ^ (row & 7)) + (tx & 3);
        qs[row][off] = acc[ri][0];
        ks[row][off] = acc[ri][1];
        vs[row][off] = acc[ri][2];
    }
    __syncthreads();

    // ---------------- phase 2: normalize rows ----------------
    {
        float sc = __expf(fminf(logit_scale[h], 4.60517019f));  // exp(min(ls, log 100))
        int r = -1; float* base = nullptr;
        if (t < NTOK) { r = t; base = &qs[r][0]; }
        else if (t >= 256 && t < 256 + NTOK) { r = t - 256; base = &ks[r][0]; sc = 1.f; }
        if (r >= 0) {
            float4* b4p = (float4*)base;
            float4 v[8];
            float ss = 0.f;
#pragma unroll
            for (int s = 0; s < 8; ++s) {
                v[s] = b4p[s];
                ss += v[s].x * v[s].x + v[s].y * v[s].y + v[s].z * v[s].z + v[s].w * v[s].w;
            }
            float rn = sc / sqrtf(ss);
#pragma unroll
            for (int s = 0; s < 8; ++s) {
                v[s].x *= rn; v[s].y *= rn; v[s].z *= rn; v[s].w *= rn;
                b4p[s] = v[s];
            }
        }
    }
    __syncthreads();

    // ---------------- phase 3: scores + softmax + PV ----------------
    const int lane = t & 63, wid = t >> 6;
    const int half = lane >> 5, d = lane & 31;

    // k rows in registers: j = lane, lane+64, 128+(lane&15) (clamped; masked later)
    float4 kr0[8], kr1[8], kr2[8];
    {
        int r0 = lane, r1 = lane + 64, r2 = 128 + (lane & 15);
#pragma unroll
        for (int s = 0; s < 8; ++s) {
            kr0[s] = ((const float4*)ks)[r0 * 8 + (s ^ (r0 & 7))];
            kr1[s] = ((const float4*)ks)[r1 * 8 + (s ^ (r1 & 7))];
            kr2[s] = ((const float4*)ks)[r2 * 8 + (s ^ (r2 & 7))];
        }
    }
    // v column d for this lane's j-half in registers
    float4 vr[18];
#pragma unroll
    for (int s18 = 0; s18 < 18; ++s18) {
        int j0 = half * 72 + 4 * s18;
        float a0 = vs[j0 + 0][4 * ((d >> 2) ^ ((j0 + 0) & 7)) + (d & 3)];
        float a1 = vs[j0 + 1][4 * ((d >> 2) ^ ((j0 + 1) & 7)) + (d & 3)];
        float a2 = vs[j0 + 2][4 * ((d >> 2) ^ ((j0 + 2) & 7)) + (d & 3)];
        float a3 = vs[j0 + 3][4 * ((d >> 2) ^ ((j0 + 3) & 7)) + (d & 3)];
        vr[s18] = make_float4(a0, a1, a2, a3);
    }

    const float* brow = bias + h * NTOK * NTOK;
    const float* mrow = mask + (b & 63) * NTOK * NTOK;
    const int j2c = 128 + (lane & 15);
    const float NEG = -1e30f;

    for (int it = 0; it < 18; ++it) {
        int i = it * 8 + wid;
        float s0 = 0.f, s1 = 0.f, s2 = 0.f;
#pragma unroll
        for (int s = 0; s < 8; ++s) {
            float4 q4 = ((const float4*)qs)[i * 8 + (s ^ (i & 7))];
            s0 += q4.x * kr0[s].x + q4.y * kr0[s].y + q4.z * kr0[s].z + q4.w * kr0[s].w;
            s1 += q4.x * kr1[s].x + q4.y * kr1[s].y + q4.z * kr1[s].z + q4.w * kr1[s].w;
            s2 += q4.x * kr2[s].x + q4.y * kr2[s].y + q4.z * kr2[s].z + q4.w * kr2[s].w;
        }
        int rowoff = i * NTOK;
        s0 += brow[rowoff + lane] + mrow[rowoff + lane];
        s1 += brow[rowoff + 64 + lane] + mrow[rowoff + 64 + lane];
        s2 += brow[rowoff + j2c] + mrow[rowoff + j2c];
        s2 = (lane < 16) ? s2 : NEG;

        float m = fmaxf(fmaxf(s0, s1), s2);
#pragma unroll
        for (int off = 32; off >= 1; off >>= 1) m = fmaxf(m, __shfl_xor(m, off));
        float e0 = __expf(s0 - m), e1 = __expf(s1 - m);
        float e2 = (lane < 16) ? __expf(s2 - m) : 0.f;
        float sum = e0 + e1 + e2;
#pragma unroll
        for (int off = 32; off >= 1; off >>= 1) sum += __shfl_xor(sum, off);
        float inv = 1.f / sum;
        ps[wid][lane] = e0 * inv;
        ps[wid][64 + lane] = e1 * inv;
        if (lane < 16) ps[wid][128 + lane] = e2 * inv;

        float o = 0.f;
        const float4* p4p = (const float4*)&ps[wid][half * 72];
#pragma unroll
        for (int s18 = 0; s18 < 18; ++s18) {
            float4 p4 = p4p[s18];
            o += p4.x * vr[s18].x + p4.y * vr[s18].y + p4.z * vr[s18].z + p4.w * vr[s18].w;
        }
        o += __shfl_xor(o, 32);
        if (lane < 32)
            attn_out[(b * NTOK + i) * CDIM + h * DHH + d] = o;
    }
}

// ---------------------------------------------------------------------------
// Kernel 4: out = attn_out @ proj_w^T + proj_b   (73728x512 @ 512x512)
// 128x128 tile, BK=16, 256 threads, 8x8 per thread (interleaved 16-stride)
// ---------------------------------------------------------------------------
__global__ __launch_bounds__(256) void proj_kernel(
    const float* __restrict__ A, const float* __restrict__ W,
    const float* __restrict__ pb, float* __restrict__ out)
{
    __shared__ float as_[16][132];
    __shared__ float bs_[16][132];
    const int t = threadIdx.x;
    const int tx = t & 15, ty = (t >> 4) & 15;
    const int m0 = blockIdx.y * 128, n0 = blockIdx.x * 128;
    float acc[8][8] = {};

    for (int kt = 0; kt < 32; ++kt) {
#pragma unroll
        for (int e = 0; e < 8; ++e) {
            int idx = e * 256 + t;             // 2048 exact
            int row = idx >> 4, kk = idx & 15;
            as_[kk][row] = A[(size_t)(m0 + row) * CDIM + kt * 16 + kk];
            bs_[kk][row] = W[(size_t)(n0 + row) * CDIM + kt * 16 + kk];
        }
        __syncthreads();
#pragma unroll
        for (int kk = 0; kk < 16; ++kk) {
            float a[8], bb[8];
#pragma unroll
            for (int i = 0; i < 8; ++i) a[i] = as_[kk][ty + 16 * i];
#pragma unroll
            for (int j = 0; j < 8; ++j) bb[j] = bs_[kk][tx + 16 * j];
#pragma unroll
            for (int i = 0; i < 8; ++i)
#pragma unroll
                for (int j = 0; j < 8; ++j)
                    acc[i][j] += a[i] * bb[j];
        }
        __syncthreads();
    }
#pragma unroll
    for (int i = 0; i < 8; ++i) {
        int m = m0 + ty + 16 * i;
#pragma unroll
        for (int j = 0; j < 8; ++j) {
            int n = n0 + tx + 16 * j;
            out[(size_t)m * CDIM + n] = acc[i][j] + pb[n];
        }
    }
}

// ---------------------------------------------------------------------------
extern "C" void kernel_launch(void* const* d_in, const int* in_sizes, int n_in,
                              void* d_out, int out_size, void* d_ws, size_t ws_size,
                              hipStream_t stream) {
    const float* x           = (const float*)d_in[0];
    const float* mask        = (const float*)d_in[1];
    const float* qkv_w       = (const float*)d_in[2];
    const float* logit_scale = (const float*)d_in[3];
    const float* cpb_w1      = (const float*)d_in[4];
    const float* cpb_b1      = (const float*)d_in[5];
    const float* cpb_w2      = (const float*)d_in[6];
    const float* proj_w      = (const float*)d_in[7];
    const float* proj_b      = (const float*)d_in[8];
    const float* rel_table   = (const float*)d_in[9];
    const int*   rel_index   = (const int*)d_in[10];
    float* out = (float*)d_out;

    // workspace layout: attn_out (151 MB) | bias (1.3 MB) | tbl (34 KB)
    char* ws = (char*)d_ws;
    float* attn_out = (float*)ws;
    float* bias = (float*)(ws + (size_t)512 * NTOK * CDIM * 4);
    float* tbl  = (float*)(ws + (size_t)512 * NTOK * CDIM * 4 + (size_t)NH * NTOK * NTOK * 4);

    cpb_mlp_kernel<<<529, 512, 0, stream>>>(rel_table, cpb_w1, cpb_b1, cpb_w2, tbl);
    bias_kernel<<<(NH * NTOK * NTOK) / 256, 256, 0, stream>>>(tbl, rel_index, bias);
    attn_kernel<<<512 * NH, 512, 0, stream>>>(x, mask, qkv_w, logit_scale, bias, attn_out);
    proj_kernel<<<dim3(4, 576), 256, 0, stream>>>(attn_out, proj_w, proj_b, out);
}